// Round 6
// baseline (285.679 us; speedup 1.0000x reference)
//
#include <hip/hip_runtime.h>
#include <math.h>

#define BQ 64
#define TBI 3000
#define DBI 128
#define TSW 375
#define TS1 188
#define DSW 192
#define NF 300
#define DMODEL 512
#define EPSLN 1e-5f

typedef __bf16 bf16x8 __attribute__((ext_vector_type(8)));
typedef float f32x4 __attribute__((ext_vector_type(4)));

__device__ __forceinline__ unsigned short f2bf(float f) {
    unsigned u = __float_as_uint(f);
    unsigned r = (u + 0x7FFFu + ((u >> 16) & 1u)) >> 16;
    return (unsigned short)r;
}

// ---------------- Kernel A: conv->LN->dot->sigmoid => alpha [B,T]; 2 rows/wave, float4 loads
__global__ __launch_bounds__(256) void k_alpha2(
    const float* __restrict__ fs, const float* __restrict__ conv_w,
    const float* __restrict__ ln_g, const float* __restrict__ ln_b,
    const float* __restrict__ wp_w, const float* __restrict__ wp_b,
    float* __restrict__ alpha_out)
{
    int wave = threadIdx.x >> 6, lane = threadIdx.x & 63;
    int l = lane & 31;
    long g = (long)blockIdx.x * 8 + wave * 2 + (lane >> 5);
    const float* row = fs + g * DBI;
    float4 f  = *(const float4*)&row[4 * l];
    float4 cw = *(const float4*)&conv_w[4 * l];
    float4 x; x.x = f.x * cw.x; x.y = f.y * cw.y; x.z = f.z * cw.z; x.w = f.w * cw.w;
    float s = x.x + x.y + x.z + x.w;
    for (int m = 16; m >= 1; m >>= 1) s += __shfl_xor(s, m, 64);
    float mu = s * (1.0f / 128.0f);
    float4 d; d.x = x.x - mu; d.y = x.y - mu; d.z = x.z - mu; d.w = x.w - mu;
    float q = d.x * d.x + d.y * d.y + d.z * d.z + d.w * d.w;
    for (int m = 16; m >= 1; m >>= 1) q += __shfl_xor(q, m, 64);
    float var = q * (1.0f / 128.0f);
    float rs = rsqrtf(var + EPSLN);
    float4 lg = *(const float4*)&ln_g[4 * l];
    float4 lb = *(const float4*)&ln_b[4 * l];
    float4 wp = *(const float4*)&wp_w[4 * l];
    float z = (d.x * rs * lg.x + lb.x) * wp.x + (d.y * rs * lg.y + lb.y) * wp.y
            + (d.z * rs * lg.z + lb.z) * wp.z + (d.w * rs * lg.w + lb.w) * wp.w;
    for (int m = 16; m >= 1; m >>= 1) z += __shfl_xor(z, m, 64);
    z += wp_b[0];
    float a = 4.0f / (1.0f + expf(-z));
    if (l == 0) alpha_out[g] = a;
}

// ---------------- Kernel B: sums (f64, wave-shuffle) + wave-scan + searchsorted
__global__ __launch_bounds__(1024) void k_scan4(
    const float* __restrict__ alpha, const int* __restrict__ tlen,
    float2* __restrict__ params, float* __restrict__ qtyo,
    float2* __restrict__ c2, float* __restrict__ tcont, int* __restrict__ ffout)
{
    __shared__ float2 sc[TBI];
    __shared__ double wsum[16];
    __shared__ float2 wpart[16];
    int b = blockIdx.x, tid = threadIdx.x;
    int wid = tid >> 6, lane = tid & 63;
    const float* ar = alpha + (long)b * TBI;
    // pass 1: f64 sum of alpha
    double s = 0.0;
    for (int t = tid; t < TBI; t += 1024) s += (double)ar[t];
    for (int m = 32; m >= 1; m >>= 1) s += __shfl_xor(s, m, 64);
    if (lane == 0) wsum[wid] = s;
    __syncthreads();
    double sum_a = 0.0;
    #pragma unroll
    for (int i = 0; i < 16; ++i) sum_a += wsum[i];
    double tgt = (double)tlen[b];
    double sa = sum_a < 1e-8 ? 1e-8 : sum_a;
    float r = (float)(tgt / sa);
    __syncthreads();
    // pass 2: f64 sum of f32(alpha*r)
    double s2 = 0.0;
    for (int t = tid; t < TBI; t += 1024) s2 += (double)(ar[t] * r);
    for (int m = 32; m >= 1; m >>= 1) s2 += __shfl_xor(s2, m, 64);
    if (lane == 0) wsum[wid] = s2;
    __syncthreads();
    double tot2 = 0.0;
    #pragma unroll
    for (int i = 0; i < 16; ++i) tot2 += wsum[i];
    float sum_cif = (float)tot2;
    float cs = ceilf(sum_cif); if (cs < 1.0f) cs = 1.0f;
    float thr = sum_cif / cs;
    float rthr = 1.0f / thr;
    if (tid == 0) {
        params[b] = make_float2(r, thr);
        atomicAdd(qtyo, fabsf((float)(sum_a - tgt)) * (1.0f / (float)BQ));
    }
    // scan: 3 elems/thread, wave shuffle-scan + cross-wave offsets
    int base = tid * 3;
    float v0x = 0.f, v0y = 0.f, v1x = 0.f, v1y = 0.f, v2x = 0.f, v2y = 0.f;
    if (base < TBI) {
        float a0 = ar[base] * r, a1 = ar[base + 1] * r, a2 = ar[base + 2] * r;
        v0x = a0 * rthr;       v0y = a0;
        v1x = v0x + a1 * rthr; v1y = v0y + a1;
        v2x = v1x + a2 * rthr; v2y = v1y + a2;
    }
    float tx = v2x, ty = v2y;
    for (int d = 1; d < 64; d <<= 1) {
        float ux = __shfl_up(tx, d, 64);
        float uy = __shfl_up(ty, d, 64);
        if (lane >= d) { tx += ux; ty += uy; }
    }
    if (lane == 63) wpart[wid] = make_float2(tx, ty);
    __syncthreads();
    float ox = tx - v2x, oy = ty - v2y;
    for (int i = 0; i < wid; ++i) { ox += wpart[i].x; oy += wpart[i].y; }
    if (base < TBI) {
        sc[base]     = make_float2(ox + v0x, oy + v0y);
        sc[base + 1] = make_float2(ox + v1x, oy + v1y);
        sc[base + 2] = make_float2(ox + v2x, oy + v2y);
    }
    __syncthreads();
    for (int t = tid; t < TBI; t += 1024) {
        float ac = ar[t] * r;
        c2[(long)b * TBI + t] = make_float2(sc[t].x, ac);
    }
    if (tid < NF) {
        float v = (float)(tid + 1) * thr;
        int lo = 0, hi = TBI;
        while (lo < hi) { int mid = (lo + hi) >> 1; if (sc[mid].y < v) lo = mid + 1; else hi = mid; }
        int ff = lo; if (ff > TBI - 1) ff = TBI - 1;
        ffout[b * NF + tid] = ff;
        int tl = ff - 1; if (tl < 0) tl = 0;
        float cum_at = sc[tl].y;
        float a_at = ar[ff] * r;
        if (a_at < 1e-8f) a_at = 1e-8f;
        float tc = (float)tl + (v - cum_at) / a_at;
        tc = fminf(fmaxf(tc, 0.0f), (float)(TBI - 1));
        tcont[b * NF + tid] = tc;
    }
}

// ---------------- Kernel D: CIF, token-owned partition — no atomics, no memset
#define TPW 3   // tokens per wave; 100 waves/batch
__global__ __launch_bounds__(256) void k_cif3(
    const float* __restrict__ fs, const float2* __restrict__ c2,
    const int* __restrict__ ffA, const float2* __restrict__ params,
    float* __restrict__ at)
{
    int wid = threadIdx.x >> 6, lane = threadIdx.x & 63;
    int wg = blockIdx.x * 4 + wid;
    int b = wg / 100, slot = wg - b * 100;
    int j0 = slot * TPW;
    const int* ffb = ffA + b * NF;
    int t0 = (j0 == 0) ? 0 : ffb[j0 - 1];
    int tE = (slot == 99) ? (TBI - 1) : ffb[j0 + TPW - 1];
    float thr = params[b].y;
    float rthr = 1.0f / thr;
    const float2* cb = c2 + (long)b * TBI;
    const float* fb = fs + (long)b * TBI * DBI;
    float* ab = at + (long)b * NF * DBI;
    int nw = j0;
    int cur = -1;
    float a0 = 0.f, a1 = 0.f;
    #define FLUSH() do { \
        if (cur >= j0 && cur < j0 + TPW) { \
            while (nw < cur) { *(float2*)&ab[nw * DBI + 2 * lane] = make_float2(0.f, 0.f); ++nw; } \
            *(float2*)&ab[cur * DBI + 2 * lane] = make_float2(a0, a1); nw = cur + 1; \
        } } while (0)
    for (int t = t0; t <= tE; ++t) {
        float2 v = cb[t];
        float2 h = *(const float2*)&fb[(long)t * DBI + 2 * lane];
        float c = v.x, ac = v.y;
        float av = ac * rthr;
        float prev = c - av;
        float kp = floorf(prev), kc = floorf(c);
        bool fired = kc > kp;
        float w_lo = fired ? (kp + 1.0f - prev) * thr : ac;
        float w_hi = fired ? (c - kc) * thr : 0.0f;
        int ip = (int)kp; if (ip > NF - 1) ip = NF - 1; if (ip < 0) ip = 0;
        int ic = (int)kc; if (ic > NF - 1) ic = NF - 1; if (ic < 0) ic = 0;
        if (ip != cur) { FLUSH(); cur = ip; a0 = 0.f; a1 = 0.f; }
        a0 += w_lo * h.x; a1 += w_lo * h.y;
        if (fired) {
            if (ic != cur) { FLUSH(); cur = ic; a0 = 0.f; a1 = 0.f; }
            a0 += w_hi * h.x; a1 += w_hi * h.y;
        }
    }
    FLUSH();
    while (nw < j0 + TPW) { *(float2*)&ab[nw * DBI + 2 * lane] = make_float2(0.f, 0.f); ++nw; }
    #undef FLUSH
}

// ---------------- Prep: weight swizzle (bf16 B-fragments) + biases + qtyo zero
__global__ __launch_bounds__(256) void k_prep2(
    const float* __restrict__ f0w, const float* __restrict__ f1w,
    const float* __restrict__ tw, const float* __restrict__ aw, const float* __restrict__ bw,
    const float* __restrict__ f0b, const float* __restrict__ f1b,
    const float* __restrict__ tb, const float* __restrict__ apb, const float* __restrict__ bpb,
    unsigned short* __restrict__ Wg, unsigned short* __restrict__ Wb,
    unsigned short* __restrict__ W2,
    float* __restrict__ gbias, float* __restrict__ bbias, float* __restrict__ bias2,
    float* __restrict__ qtyo)
{
    if (blockIdx.x == 1216) {
        for (int c = threadIdx.x; c < 512; c += 256) {
            if (c < 384) {
                gbias[c] = c < 192 ? f0b[c] : f1b[c - 192];
                bbias[c] = c < 192 ? f0b[c + 192] : f1b[c - 192 + 192];
            }
            bias2[c] = tb[c] + apb[c] + bpb[c];
        }
        if (threadIdx.x == 0) qtyo[0] = 0.f;
        return;
    }
    int i = blockIdx.x * 256 + threadIdx.x;
    if (i < 49152) {                       // film gamma/beta: K=128 (KT=4), N=384 (NT=24)
        int j = i & 7, lane = (i >> 3) & 63, kt = (i >> 9) & 3, nt = i >> 11;
        int k = kt * 32 + (lane >> 4) * 8 + j;
        int n = nt * 16 + (lane & 15);
        float g, b;
        if (n < 192) { g = f0w[k * 384 + n];         b = f0w[k * 384 + n + 192]; }
        else         { g = f1w[k * 384 + (n - 192)]; b = f1w[k * 384 + (n - 192) + 192]; }
        Wg[i] = f2bf(g); Wb[i] = f2bf(b);
    } else {                               // W2 stacked [tw;aw;bw]: K=512 (KT=16), N=512 (NT=32)
        int ii = i - 49152;
        int j = ii & 7, lane = (ii >> 3) & 63, kt = (ii >> 9) & 15, nt = ii >> 13;
        int k = kt * 32 + (lane >> 4) * 8 + j;
        int n = nt * 16 + (lane & 15);
        float v;
        if (k < 128)      v = tw[k * 512 + n];
        else if (k < 320) v = aw[(k - 128) * 512 + n];
        else              v = bw[(k - 320) * 512 + n];
        W2[ii] = f2bf(v);
    }
}

// ---------------- Kernel E1: FiLM GEMM + interp epilogue -> Xs (A-fragment layout, bf16)
#define EROWS 16
__global__ __launch_bounds__(512) void k_film(
    const float* __restrict__ at, const float* __restrict__ tcont,
    const float* __restrict__ src0, const float* __restrict__ src1,
    const unsigned short* __restrict__ Wg, const unsigned short* __restrict__ Wb,
    const float* __restrict__ gbias, const float* __restrict__ bbias,
    unsigned short* __restrict__ Xs)
{
    __shared__ __align__(16) unsigned short X[EROWS][520];
    __shared__ float s_w0[EROWS], s_w1[EROWS];
    __shared__ int s_lo0[EROWS], s_lo1[EROWS], s_b[EROWS];
    int tid = threadIdx.x;
    int wave = tid >> 6, lane = tid & 63;
    long r0 = (long)blockIdx.x * EROWS;
    {
        int r = tid >> 5, k4 = (tid & 31) * 4;
        float4 v = *(const float4*)&at[(r0 + r) * DBI + k4];
        X[r][k4 + 0] = f2bf(v.x); X[r][k4 + 1] = f2bf(v.y);
        X[r][k4 + 2] = f2bf(v.z); X[r][k4 + 3] = f2bf(v.w);
    }
    if (tid < EROWS) {
        long g = r0 + tid;
        s_b[tid] = (int)(g / NF);
        float tc = tcont[g];
        float t0 = tc * ((float)TSW / 3000.0f);
        int lo0 = (int)t0; if (lo0 > TSW - 2) lo0 = TSW - 2; if (lo0 < 0) lo0 = 0;
        s_lo0[tid] = lo0; s_w0[tid] = t0 - (float)lo0;
        float t1 = tc * ((float)TS1 / 3000.0f);
        int lo1 = (int)t1; if (lo1 > TS1 - 2) lo1 = TS1 - 2; if (lo1 < 0) lo1 = 0;
        s_lo1[tid] = lo1; s_w1[tid] = t1 - (float)lo1;
    }
    __syncthreads();
    int mrow = lane & 15, quad = lane >> 4;
    for (int nt = wave; nt < 24; nt += 8) {
        f32x4 ag = {0,0,0,0}, ab = {0,0,0,0};
        #pragma unroll
        for (int kt = 0; kt < 4; ++kt) {
            bf16x8 a = *(const bf16x8*)&X[mrow][kt * 32 + quad * 8];
            bf16x8 bg = *(const bf16x8*)&Wg[(((nt * 4 + kt) * 64) + lane) * 8];
            bf16x8 bb = *(const bf16x8*)&Wb[(((nt * 4 + kt) * 64) + lane) * 8];
            ag = __builtin_amdgcn_mfma_f32_16x16x32_bf16(a, bg, ag, 0, 0, 0);
            ab = __builtin_amdgcn_mfma_f32_16x16x32_bf16(a, bb, ab, 0, 0, 0);
        }
        int c = nt * 16 + mrow;
        bool sel = c >= DSW;
        int cc = sel ? c - DSW : c;
        const float* S = sel ? src1 : src0;
        int Ts = sel ? TS1 : TSW;
        float gb = gbias[c], bbv = bbias[c];
        #pragma unroll
        for (int q = 0; q < 4; ++q) {
            int r = quad * 4 + q;
            int b = s_b[r];
            int lo = sel ? s_lo1[r] : s_lo0[r];
            float w = sel ? s_w1[r] : s_w0[r];
            const float* Sp = S + ((long)b * Ts + lo) * DSW + cc;
            float pv = (1.0f - w) * Sp[0] + w * Sp[DSW];
            X[r][128 + c] = f2bf((ag[q] + gb) * pv + (ab[q] + bbv));
        }
    }
    __syncthreads();
    // write out in MFMA-A-fragment order: Xs[((mt*16+kt)*64+lane)*8 + j] = X[lane&15][kt*32+(lane>>4)*8+j]
    long mt = blockIdx.x;
    int l = tid & 63;
    int ktb = tid >> 6;
    #pragma unroll
    for (int i = 0; i < 2; ++i) {
        int kk = ktb + i * 8;
        uint4 v = *(const uint4*)&X[l & 15][kk * 32 + (l >> 4) * 8];
        *(uint4*)&Xs[((mt * 16 + kk) * 64 + l) * 8] = v;
    }
}

// ---------------- Kernel E2: persistent-B GEMM: embs[19200,512] = Xs @ W2 + bias2
__global__ __launch_bounds__(512, 4) void k_gemm(
    const unsigned short* __restrict__ Xs, const unsigned short* __restrict__ W2,
    const float* __restrict__ bias2, float* __restrict__ embs)
{
    int tid = threadIdx.x;
    int wave = tid >> 6, lane = tid & 63;
    int ngrp = blockIdx.x & 3, mgrp = blockIdx.x >> 2;   // 4 N-groups x 128 M-groups
    int nt = ngrp * 8 + wave;                            // n-tile 0..31, B held in regs
    bf16x8 b[16];
    #pragma unroll
    for (int kt = 0; kt < 16; ++kt)
        b[kt] = *(const bf16x8*)&W2[((nt * 16 + kt) * 64 + lane) * 8];
    int col = nt * 16 + (lane & 15);
    float bv = bias2[col];
    for (int mt = mgrp; mt < 1200; mt += 128) {
        const unsigned short* xp = Xs + (long)mt * 16 * 64 * 8;
        f32x4 acc = {0, 0, 0, 0};
        bf16x8 a[4];
        #pragma unroll
        for (int j = 0; j < 4; ++j) a[j] = *(const bf16x8*)&xp[(j * 64 + lane) * 8];
        #pragma unroll
        for (int kb = 0; kb < 16; kb += 4) {
            bf16x8 an[4];
            if (kb < 12) {
                #pragma unroll
                for (int j = 0; j < 4; ++j)
                    an[j] = *(const bf16x8*)&xp[((kb + 4 + j) * 64 + lane) * 8];
            }
            #pragma unroll
            for (int j = 0; j < 4; ++j)
                acc = __builtin_amdgcn_mfma_f32_16x16x32_bf16(a[j], b[kb + j], acc, 0, 0, 0);
            #pragma unroll
            for (int j = 0; j < 4; ++j) a[j] = an[j];
        }
        int rowb = mt * 16 + (lane >> 4) * 4;
        #pragma unroll
        for (int q = 0; q < 4; ++q)
            embs[(long)(rowb + q) * DMODEL + col] = acc[q] + bv;
    }
}

extern "C" void kernel_launch(void* const* d_in, const int* in_sizes, int n_in,
                              void* d_out, int out_size, void* d_ws, size_t ws_size,
                              hipStream_t stream)
{
    const float* fs     = (const float*)d_in[0];
    const float* src0   = (const float*)d_in[1];
    const float* src1   = (const float*)d_in[2];
    const int*   tlen   = (const int*)d_in[3];
    const float* conv_w = (const float*)d_in[4];
    const float* ln_g   = (const float*)d_in[5];
    const float* ln_b   = (const float*)d_in[6];
    const float* wp_w   = (const float*)d_in[7];
    const float* wp_b   = (const float*)d_in[8];
    const float* f0w    = (const float*)d_in[9];
    const float* f0b    = (const float*)d_in[10];
    const float* f1w    = (const float*)d_in[11];
    const float* f1b    = (const float*)d_in[12];
    const float* tw     = (const float*)d_in[13];
    const float* tb     = (const float*)d_in[14];
    const float* aw     = (const float*)d_in[15];
    const float* apb    = (const float*)d_in[16];
    const float* bw     = (const float*)d_in[17];
    const float* bpb    = (const float*)d_in[18];

    float* embs  = (float*)d_out;
    float* alpha = embs + (long)BQ * NF * DMODEL;
    float* qtyo  = alpha + (long)BQ * TBI;

    char* ws = (char*)d_ws;
    size_t off = 0;
    float*  at     = (float*)(ws + off);  off += 9830400;
    float2* c2     = (float2*)(ws + off); off += 1536000;
    float*  tcont  = (float*)(ws + off);  off += 76800;
    int*    ffA    = (int*)(ws + off);    off += 76800;
    float2* params = (float2*)(ws + off); off += 512;
    unsigned short* Wg = (unsigned short*)(ws + off); off += 98304;
    unsigned short* Wb = (unsigned short*)(ws + off); off += 98304;
    unsigned short* W2 = (unsigned short*)(ws + off); off += 524288;
    float* gbias = (float*)(ws + off); off += 1536;
    float* bbias = (float*)(ws + off); off += 1536;
    float* bias2 = (float*)(ws + off); off += 2048;
    unsigned short* Xs = (unsigned short*)(ws + off); off += 19660800;

    k_prep2<<<1217, 256, 0, stream>>>(f0w, f1w, tw, aw, bw, f0b, f1b, tb, apb, bpb,
                                      Wg, Wb, W2, gbias, bbias, bias2, qtyo);
    k_alpha2<<<(BQ * TBI) / 8, 256, 0, stream>>>(fs, conv_w, ln_g, ln_b, wp_w, wp_b, alpha);
    k_scan4<<<BQ, 1024, 0, stream>>>(alpha, tlen, params, qtyo, c2, tcont, ffA);
    k_cif3<<<(BQ * 100) / 4, 256, 0, stream>>>(fs, c2, ffA, params, at);
    k_film<<<(BQ * NF) / EROWS, 512, 0, stream>>>(at, tcont, src0, src1,
                                                  Wg, Wb, gbias, bbias, Xs);
    k_gemm<<<512, 512, 0, stream>>>(Xs, W2, bias2, embs);
}